// Round 12
// baseline (135.683 us; speedup 1.0000x reference)
//
#include <hip/hip_runtime.h>
#include <hip/hip_bf16.h>

#define B_ 2
#define T_ 2048
#define C_ 1024
#define H_ 16
#define D_ 64
#define M_ (B_*T_)          // 4096 rows
#define SCALE_ 0.125f       // 1/sqrt(64)
#define LOG2E_ 1.44269504f
#define NEG_ (-1e30f)
#define THR_ 8.0f           // defer-max threshold (log2 units)

typedef __bf16 bf16;
typedef __bf16 bf16x4 __attribute__((ext_vector_type(4)));
typedef __bf16 bf16x8 __attribute__((ext_vector_type(8)));
typedef float  f32x4  __attribute__((ext_vector_type(4)));

#define XB_ELEMS  ((size_t)M_*C_)        // 4,194,304
#define W_ELEMS   ((size_t)C_*C_)        // 1,048,576

__device__ __forceinline__ void glds16(const void* g, void* l) {
  __builtin_amdgcn_global_load_lds((const __attribute__((address_space(1))) void*)g,
                                   (__attribute__((address_space(3))) void*)l,
                                   16, 0, 0);
}

// ---------------------------------------------------------------------------
// f32 -> bf16 conversion pass (unchanged).
// ---------------------------------------------------------------------------
__global__ __launch_bounds__(256)
void cvt5(const float* __restrict__ x,  const float* __restrict__ wq,
          const float* __restrict__ wk, const float* __restrict__ wv,
          const float* __restrict__ wo, bf16* __restrict__ out) {
  int bid = blockIdx.x;
  const float* src; bf16* dst; size_t off;
  if (bid < 2048)      { src = x;  dst = out;                         off = (size_t)bid*2048; }
  else if (bid < 2560) { src = wq; dst = out + XB_ELEMS;              off = (size_t)(bid-2048)*2048; }
  else if (bid < 3072) { src = wk; dst = out + XB_ELEMS +   W_ELEMS;  off = (size_t)(bid-2560)*2048; }
  else if (bid < 3584) { src = wv; dst = out + XB_ELEMS + 2*W_ELEMS;  off = (size_t)(bid-3072)*2048; }
  else                 { src = wo; dst = out + XB_ELEMS + 3*W_ELEMS;  off = (size_t)(bid-3584)*2048; }
  size_t i = off + (size_t)threadIdx.x * 8;
  f32x4 lo = *(const f32x4*)(src + i);
  f32x4 hi = *(const f32x4*)(src + i + 4);
  bf16x8 r;
  #pragma unroll
  for (int t = 0; t < 4; ++t) { r[t] = (bf16)lo[t]; r[t+4] = (bf16)hi[t]; }
  *(bf16x8*)(dst + i) = r;
}

// ---------------------------------------------------------------------------
// NT GEMM (MFMA, pure bf16, glds16 + 2-phase LDS double-buffer + XCD swizzle):
// C[m,n] = sum_k A[m,k] * W[n,k]. 128x128 tile, BK=32, 4 waves, linear LDS.
// 1D grid. OUTMODE 0 (nwg=768): id2 = z*256 + mt*8 + nt;
//   z=0 -> Q*(SCALE*log2e) [B,H,T,D]; z=1 -> K [B,H,T,D]; z=2 -> V^T [B,H,D,T]
// OUTMODE 1 (nwg=256): id2 = mt*8 + nt; OUT = f32 [M,C]
// ---------------------------------------------------------------------------
template<int OUTMODE>
__global__ __launch_bounds__(256)
void gemm_nt(const bf16* __restrict__ Ab,
             const bf16* __restrict__ W0, const bf16* __restrict__ W1,
             const bf16* __restrict__ W2,
             void* __restrict__ O0v, void* __restrict__ O1v, void* __restrict__ O2v,
             int K) {
  __shared__ __align__(16) bf16 As[2][128*32];
  __shared__ __align__(16) bf16 Bs[2][128*32];

  // --- block decode with bijective XCD swizzle (XCD = id&7 gets contiguous id2)
  const int nwg = (OUTMODE == 0) ? 768 : 256;
  const int id = blockIdx.x;
  const int id2 = (id & 7) * (nwg >> 3) + (id >> 3);
  int z, r;
  if constexpr (OUTMODE == 0) { z = id2 >> 8; r = id2 & 255; }
  else                        { z = 0;        r = id2;       }
  const int m0 = (r >> 3) * 128;
  const int n0 = (r & 7) * 128;

  const bf16* W = W0;
  void* Ov = O0v;
  bool vtrans = false;
  float oscale = 1.0f;
  if constexpr (OUTMODE == 0) {
    if (z == 0)      { oscale = SCALE_ * LOG2E_; }
    else if (z == 1) { W = W1; Ov = O1v; }
    else             { W = W2; Ov = O2v; vtrans = true; }
  }

  const int tid = threadIdx.x, wid = tid >> 6, lane = tid & 63;
  const int wm = wid >> 1, wn = wid & 1;
  const int l15 = lane & 15, grp = lane >> 4;

  f32x4 acc[4][4] = {};

  // glds16 staging: chunk c (16 rows x 32k = 1KB); wave handles c0=wid, c1=wid+4.
  const int lr = lane >> 2, lk = (lane & 3) * 8;
  const int c0 = wid, c1 = wid + 4;
  const bf16* Ag0 = Ab + (size_t)(m0 + c0*16 + lr) * K + lk;
  const bf16* Ag1 = Ab + (size_t)(m0 + c1*16 + lr) * K + lk;
  const bf16* Bg0 = W  + (size_t)(n0 + c0*16 + lr) * K + lk;
  const bf16* Bg1 = W  + (size_t)(n0 + c1*16 + lr) * K + lk;

  const int amRow = wm*64 + l15;
  const int bnRow = wn*64 + l15;
  const int kSlot = grp * 8;

  // prologue: stage tile 0 into buffer 0
  glds16(Ag0, &As[0][c0*512]);
  glds16(Ag1, &As[0][c1*512]);
  glds16(Bg0, &Bs[0][c0*512]);
  glds16(Bg1, &Bs[0][c1*512]);
  __syncthreads();                       // vmcnt drained -> tile 0 ready

  int cur = 0;
  for (int k0 = 0; k0 < K; k0 += 32) {
    // issue next tile's loads into the other buffer (overlaps with compute)
    if (k0 + 32 < K) {
      const int kn = k0 + 32;
      bf16* Ad = &As[cur^1][0];
      bf16* Bd = &Bs[cur^1][0];
      glds16(Ag0 + kn, Ad + c0*512);
      glds16(Ag1 + kn, Ad + c1*512);
      glds16(Bg0 + kn, Bd + c0*512);
      glds16(Bg1 + kn, Bd + c1*512);
    }

    const bf16* Ac = &As[cur][0];
    const bf16* Bc = &Bs[cur][0];
    bf16x8 af[4], bfr[4];
    #pragma unroll
    for (int i = 0; i < 4; ++i) {
      af[i]  = *(const bf16x8*)(Ac + (amRow + i*16)*32 + kSlot);
      bfr[i] = *(const bf16x8*)(Bc + (bnRow + i*16)*32 + kSlot);
    }
    #pragma unroll
    for (int i = 0; i < 4; ++i)
      #pragma unroll
      for (int j = 0; j < 4; ++j)
        acc[i][j] = __builtin_amdgcn_mfma_f32_16x16x32_bf16(af[i], bfr[j], acc[i][j], 0, 0, 0);

    __syncthreads();                     // drains vmcnt: next tile landed; reads done
    cur ^= 1;
  }

  // epilogue: C/D layout col=lane&15, row=(lane>>4)*4+reg
  const int rBase = m0 + wm*64 + grp * 4;
  const int cBase = n0 + wn*64 + l15;
  #pragma unroll
  for (int fm = 0; fm < 4; ++fm) {
    #pragma unroll
    for (int fn = 0; fn < 4; ++fn) {
      #pragma unroll
      for (int j = 0; j < 4; ++j) {
        int m = rBase + fm*16 + j;
        int n = cBase + fn*16;
        if constexpr (OUTMODE == 0) {
          int b = m >> 11, t = m & 2047, h = n >> 6, d = n & 63;
          size_t idx = vtrans ? (((size_t)(b*H_ + h) * D_ + d) * T_ + t)
                              : (((size_t)(b*H_ + h) * T_ + t) * D_ + d);
          ((bf16*)Ov)[idx] = (bf16)(acc[fm][fn][j] * oscale);
        } else {
          ((float*)Ov)[(size_t)m * C_ + n] = acc[fm][fn][j];
        }
      }
    }
  }
}

// ---------------------------------------------------------------------------
// Flash attention, causal (unchanged from round 11).
// ---------------------------------------------------------------------------
#define LKV 72

__global__ __launch_bounds__(256)
void attn_fwd(const bf16* __restrict__ Q, const bf16* __restrict__ Km,
              const bf16* __restrict__ Vt, bf16* __restrict__ Oa) {
  __shared__ __align__(16) bf16 Ks [64*LKV];
  __shared__ __align__(16) bf16 Vts[64*LKV];
  __shared__ __align__(16) bf16 Ps [64*LKV];

  const int id = blockIdx.x;
  const int qt = 31 - (id >> 5);
  const int bh = id & 31;
  const int q0 = qt * 64;
  const int tid = threadIdx.x, wid = tid >> 6, lane = tid & 63;
  const int l15 = lane & 15;
  const int grp = lane >> 4;
  const int myrow4 = grp * 4;

  const bf16* Qb = Q  + (size_t)bh * T_ * D_;
  const bf16* Kb = Km + (size_t)bh * T_ * D_;
  const bf16* Vb = Vt + (size_t)bh * D_ * T_;

  const int ksr = tid >> 3, kskc = tid & 7;
  const int kSlot = grp * 8;
  const int b = bh >> 4, h = bh & 15;

  const int qrow = q0 + wid*16 + l15;
  bf16x8 aq0 = *(const bf16x8*)(Qb + (size_t)qrow*64 +      grp*8);
  bf16x8 aq1 = *(const bf16x8*)(Qb + (size_t)qrow*64 + 32 + grp*8);

  f32x4 oacc[4] = {};
  float m_s = NEG_, l_s = 0.f;

  bf16x8 kv_a = *(const bf16x8*)(Kb + (size_t)(ksr)*64      + kskc*8);
  bf16x8 kv_b = *(const bf16x8*)(Kb + (size_t)(ksr + 32)*64 + kskc*8);
  bf16x8 vt_a = *(const bf16x8*)(Vb + (size_t)(ksr     )*T_ + kskc*8);
  bf16x8 vt_b = *(const bf16x8*)(Vb + (size_t)(ksr + 32)*T_ + kskc*8);

  for (int kt = 0; kt <= qt; ++kt) {
    const int kv0 = kt * 64;

    __syncthreads();
    *(bf16x8*)(Ks  + ksr*LKV      + kskc*8) = kv_a;
    *(bf16x8*)(Ks  + (ksr+32)*LKV + kskc*8) = kv_b;
    *(bf16x8*)(Vts + ksr*LKV      + kskc*8) = vt_a;
    *(bf16x8*)(Vts + (ksr+32)*LKV + kskc*8) = vt_b;
    __syncthreads();

    {
      const int kn = (kt < qt) ? kv0 + 64 : kv0;
      kv_a = *(const bf16x8*)(Kb + (size_t)(kn + ksr)*64      + kskc*8);
      kv_b = *(const bf16x8*)(Kb + (size_t)(kn + ksr + 32)*64 + kskc*8);
      vt_a = *(const bf16x8*)(Vb + (size_t)(ksr     )*T_ + kn + kskc*8);
      vt_b = *(const bf16x8*)(Vb + (size_t)(ksr + 32)*T_ + kn + kskc*8);
    }

    f32x4 s[4];
    #pragma unroll
    for (int n = 0; n < 4; ++n) {
      int row = n*16 + l15;
      bf16x8 bk0 = *(const bf16x8*)(Ks + row*LKV      + kSlot);
      bf16x8 bk1 = *(const bf16x8*)(Ks + row*LKV + 32 + kSlot);
      f32x4 a = {};
      a = __builtin_amdgcn_mfma_f32_16x16x32_bf16(bk0, aq0, a, 0, 0, 0);
      a = __builtin_amdgcn_mfma_f32_16x16x32_bf16(bk1, aq1, a, 0, 0, 0);
      s[n] = a;
    }

    float pmax = NEG_;
    if (kt == qt) {
      #pragma unroll
      for (int n = 0; n < 4; ++n)
        #pragma unroll
        for (int j = 0; j < 4; ++j) {
          int kvg = kv0 + n*16 + myrow4 + j;
          float sv = (kvg <= qrow) ? s[n][j] : NEG_;
          s[n][j] = sv;
          pmax = fmaxf(pmax, sv);
        }
    } else {
      #pragma unroll
      for (int n = 0; n < 4; ++n)
        #pragma unroll
        for (int j = 0; j < 4; ++j) pmax = fmaxf(pmax, s[n][j]);
    }
    pmax = fmaxf(pmax, __shfl_xor(pmax, 16));
    pmax = fmaxf(pmax, __shfl_xor(pmax, 32));

    if (__any(pmax > m_s + THR_)) {
      float mnew = fmaxf(m_s, pmax);
      float scold = __builtin_amdgcn_exp2f(m_s - mnew);
      m_s = mnew;
      l_s *= scold;
      #pragma unroll
      for (int j = 0; j < 4; ++j) {
        float scj = __shfl(scold, myrow4 + j);
        #pragma unroll
        for (int n = 0; n < 4; ++n) oacc[n][j] *= scj;
      }
    }

    float ps = 0.f;
    #pragma unroll
    for (int n = 0; n < 4; ++n) {
      bf16x4 pw;
      #pragma unroll
      for (int j = 0; j < 4; ++j) {
        float p = __builtin_amdgcn_exp2f(s[n][j] - m_s);
        ps += p;
        pw[j] = (bf16)p;
      }
      *(bf16x4*)(Ps + (size_t)(wid*16 + l15)*LKV + n*16 + myrow4) = pw;
    }
    ps += __shfl_xor(ps, 16);
    ps += __shfl_xor(ps, 32);
    l_s += ps;

    asm volatile("s_waitcnt lgkmcnt(0)" ::: "memory");
    __builtin_amdgcn_sched_barrier(0);

    int parow = wid*16 + l15;
    bf16x8 pa0 = *(const bf16x8*)(Ps + parow*LKV      + kSlot);
    bf16x8 pa1 = *(const bf16x8*)(Ps + parow*LKV + 32 + kSlot);
    #pragma unroll
    for (int n = 0; n < 4; ++n) {
      int vrow = n*16 + l15;
      bf16x8 bv0 = *(const bf16x8*)(Vts + vrow*LKV      + kSlot);
      bf16x8 bv1 = *(const bf16x8*)(Vts + vrow*LKV + 32 + kSlot);
      oacc[n] = __builtin_amdgcn_mfma_f32_16x16x32_bf16(pa0, bv0, oacc[n], 0, 0, 0);
      oacc[n] = __builtin_amdgcn_mfma_f32_16x16x32_bf16(pa1, bv1, oacc[n], 0, 0, 0);
    }
  }

  const int tg = q0 + wid*16 + myrow4;
  #pragma unroll
  for (int j = 0; j < 4; ++j) {
    float lj = __shfl(l_s, myrow4 + j);
    float inv = 1.f / lj;
    int trow = tg + j;
    #pragma unroll
    for (int n = 0; n < 4; ++n) {
      int ch = h*64 + n*16 + l15;
      Oa[((size_t)(b*T_ + trow)) * C_ + ch] = (bf16)(oacc[n][j] * inv);
    }
  }
}

// ---------------------------------------------------------------------------
extern "C" void kernel_launch(void* const* d_in, const int* in_sizes, int n_in,
                              void* d_out, int out_size, void* d_ws, size_t ws_size,
                              hipStream_t stream) {
  const float* x  = (const float*)d_in[0];
  const float* wq = (const float*)d_in[1];
  const float* wk = (const float*)d_in[2];
  const float* wv = (const float*)d_in[3];
  const float* wo = (const float*)d_in[4];

  bf16* q  = (bf16*)d_ws;                    // [B,H,T,D] bf16 (Q pre-scaled)
  bf16* k  = q  + XB_ELEMS;
  bf16* v  = k  + XB_ELEMS;                  // [B,H,D,T] bf16 (transposed)

  bf16* cvtbuf = (bf16*)d_out;               // bf16 staging inside d_out
  bf16* xb  = cvtbuf;                        // [M,K] bf16
  bf16* wqb = cvtbuf + XB_ELEMS;
  bf16* wkb = wqb + W_ELEMS;
  bf16* wvb = wkb + W_ELEMS;
  bf16* wob = wvb + W_ELEMS;                 // exactly fills d_out

  dim3 blk(256);
  // 0) convert all f32 inputs to bf16 (into d_out)
  cvt5<<<dim3(4096), blk, 0, stream>>>(x, wq, wk, wv, wo, cvtbuf);
  // 1) QKV projections (bf16, glds16, dbuf, XCD-swizzled): xb @ W^T -> q,k,v
  gemm_nt<0><<<dim3(768), blk, 0, stream>>>(xb, wqb, wkb, wvb, q, k, v, C_);
  // 2) causal flash attention -> ao bf16 [B,T,C] into xb slot (x dead)
  attn_fwd<<<dim3(1024), blk, 0, stream>>>(q, k, v, xb);
  // 3) relocate ao and wo_bf16 into ws (q,k slots dead after attention)
  hipMemcpyAsync(q, xb,  XB_ELEMS * sizeof(bf16), hipMemcpyDeviceToDevice, stream);
  hipMemcpyAsync(k, wob, W_ELEMS  * sizeof(bf16), hipMemcpyDeviceToDevice, stream);
  // 4) output projection: ao @ wo^T -> f32 d_out
  gemm_nt<1><<<dim3(256), blk, 0, stream>>>(q, k, nullptr, nullptr,
                                            d_out, nullptr, nullptr, C_);
}

// Round 13
// 133.491 us; speedup vs baseline: 1.0164x; 1.0164x over previous
//
#include <hip/hip_runtime.h>
#include <hip/hip_bf16.h>

#define B_ 2
#define T_ 2048
#define C_ 1024
#define H_ 16
#define D_ 64
#define M_ (B_*T_)          // 4096 rows
#define SCALE_ 0.125f       // 1/sqrt(64)
#define LOG2E_ 1.44269504f
#define NEG_ (-1e30f)
#define THR_ 8.0f           // defer-max threshold (log2 units)

typedef __bf16 bf16;
typedef __bf16 bf16x4 __attribute__((ext_vector_type(4)));
typedef __bf16 bf16x8 __attribute__((ext_vector_type(8)));
typedef float  f32x4  __attribute__((ext_vector_type(4)));

#define XB_ELEMS  ((size_t)M_*C_)        // 4,194,304
#define W_ELEMS   ((size_t)C_*C_)        // 1,048,576

__device__ __forceinline__ void glds16(const void* g, void* l) {
  __builtin_amdgcn_global_load_lds((const __attribute__((address_space(1))) void*)g,
                                   (__attribute__((address_space(3))) void*)l,
                                   16, 0, 0);
}

// ---------------------------------------------------------------------------
// f32 -> bf16 conversion pass (unchanged).
// ---------------------------------------------------------------------------
__global__ __launch_bounds__(256)
void cvt5(const float* __restrict__ x,  const float* __restrict__ wq,
          const float* __restrict__ wk, const float* __restrict__ wv,
          const float* __restrict__ wo, bf16* __restrict__ out) {
  int bid = blockIdx.x;
  const float* src; bf16* dst; size_t off;
  if (bid < 2048)      { src = x;  dst = out;                         off = (size_t)bid*2048; }
  else if (bid < 2560) { src = wq; dst = out + XB_ELEMS;              off = (size_t)(bid-2048)*2048; }
  else if (bid < 3072) { src = wk; dst = out + XB_ELEMS +   W_ELEMS;  off = (size_t)(bid-2560)*2048; }
  else if (bid < 3584) { src = wv; dst = out + XB_ELEMS + 2*W_ELEMS;  off = (size_t)(bid-3072)*2048; }
  else                 { src = wo; dst = out + XB_ELEMS + 3*W_ELEMS;  off = (size_t)(bid-3584)*2048; }
  size_t i = off + (size_t)threadIdx.x * 8;
  f32x4 lo = *(const f32x4*)(src + i);
  f32x4 hi = *(const f32x4*)(src + i + 4);
  bf16x8 r;
  #pragma unroll
  for (int t = 0; t < 4; ++t) { r[t] = (bf16)lo[t]; r[t+4] = (bf16)hi[t]; }
  *(bf16x8*)(dst + i) = r;
}

// ---------------------------------------------------------------------------
// NT GEMM (MFMA, bf16, glds16, 2-buffer pipeline with COUNTED vmcnt + raw
// barriers — vmcnt never drains to 0 in the main loop). 128x128, BK=32,
// 4 waves, linear LDS, XCD-swizzled 1D grid.
// OUTMODE 0 (nwg=768): z=0 -> Q*(SCALE*log2e) [B,H,T,D]; z=1 -> K; z=2 -> V^T
// OUTMODE 1 (nwg=256): OUT = f32 [M,C]
// ---------------------------------------------------------------------------
template<int OUTMODE>
__global__ __launch_bounds__(256)
void gemm_nt(const bf16* __restrict__ Ab,
             const bf16* __restrict__ W0, const bf16* __restrict__ W1,
             const bf16* __restrict__ W2,
             void* __restrict__ O0v, void* __restrict__ O1v, void* __restrict__ O2v,
             int K) {
  __shared__ __align__(16) bf16 As[2][128*32];
  __shared__ __align__(16) bf16 Bs[2][128*32];

  const int nwg = (OUTMODE == 0) ? 768 : 256;
  const int id = blockIdx.x;
  const int id2 = (id & 7) * (nwg >> 3) + (id >> 3);
  int z, r;
  if constexpr (OUTMODE == 0) { z = id2 >> 8; r = id2 & 255; }
  else                        { z = 0;        r = id2;       }
  const int m0 = (r >> 3) * 128;
  const int n0 = (r & 7) * 128;

  const bf16* W = W0;
  void* Ov = O0v;
  bool vtrans = false;
  float oscale = 1.0f;
  if constexpr (OUTMODE == 0) {
    if (z == 0)      { oscale = SCALE_ * LOG2E_; }
    else if (z == 1) { W = W1; Ov = O1v; }
    else             { W = W2; Ov = O2v; vtrans = true; }
  }

  const int tid = threadIdx.x, wid = tid >> 6, lane = tid & 63;
  const int wm = wid >> 1, wn = wid & 1;
  const int l15 = lane & 15, grp = lane >> 4;

  f32x4 acc[4][4] = {};

  // glds16 staging: chunk c = 16 rows x 32k (1KB); wave w stages c0=w, c1=w+4.
  const int lr = lane >> 2, lk = (lane & 3) * 8;
  const int c0 = wid, c1 = wid + 4;
  const bf16* Ag0 = Ab + (size_t)(m0 + c0*16 + lr) * K + lk;
  const bf16* Ag1 = Ab + (size_t)(m0 + c1*16 + lr) * K + lk;
  const bf16* Bg0 = W  + (size_t)(n0 + c0*16 + lr) * K + lk;
  const bf16* Bg1 = W  + (size_t)(n0 + c1*16 + lr) * K + lk;

  const int amRow = wm*64 + l15;
  const int bnRow = wn*64 + l15;
  const int kSlot = grp * 8;

  const int NT = K >> 5;                 // 32 k-tiles

  // prologue: stage tiles 0 and 1 (8 loads in flight per wave)
  glds16(Ag0,      &As[0][c0*512]);
  glds16(Ag1,      &As[0][c1*512]);
  glds16(Bg0,      &Bs[0][c0*512]);
  glds16(Bg1,      &Bs[0][c1*512]);
  glds16(Ag0 + 32, &As[1][c0*512]);
  glds16(Ag1 + 32, &As[1][c1*512]);
  glds16(Bg0 + 32, &Bs[1][c0*512]);
  glds16(Bg1 + 32, &Bs[1][c1*512]);

  for (int t = 0; t < NT; ++t) {
    // tile t's 4 loads complete; tile t+1's 4 may remain in flight
    if (t < NT - 1) asm volatile("s_waitcnt vmcnt(4)" ::: "memory");
    else            asm volatile("s_waitcnt vmcnt(0)" ::: "memory");
    __builtin_amdgcn_sched_barrier(0);
    __builtin_amdgcn_s_barrier();        // raw: no vmcnt(0) drain

    const bf16* Ac = As[t & 1];
    const bf16* Bc = Bs[t & 1];
    bf16x8 af[4], bfr[4];
    #pragma unroll
    for (int i = 0; i < 4; ++i) {
      af[i]  = *(const bf16x8*)(Ac + (amRow + i*16)*32 + kSlot);
      bfr[i] = *(const bf16x8*)(Bc + (bnRow + i*16)*32 + kSlot);
    }
    __builtin_amdgcn_s_setprio(1);
    #pragma unroll
    for (int i = 0; i < 4; ++i)
      #pragma unroll
      for (int j = 0; j < 4; ++j)
        acc[i][j] = __builtin_amdgcn_mfma_f32_16x16x32_bf16(af[i], bfr[j], acc[i][j], 0, 0, 0);
    __builtin_amdgcn_s_setprio(0);

    __builtin_amdgcn_s_barrier();        // all waves done reading buf[t&1]

    if (t + 2 < NT) {                    // stage tile t+2 into the freed buffer
      const int kn = (t + 2) * 32;
      bf16* Ad = As[t & 1];
      bf16* Bd = Bs[t & 1];
      glds16(Ag0 + kn, Ad + c0*512);
      glds16(Ag1 + kn, Ad + c1*512);
      glds16(Bg0 + kn, Bd + c0*512);
      glds16(Bg1 + kn, Bd + c1*512);
    }
  }

  // epilogue: C/D layout col=lane&15, row=(lane>>4)*4+reg
  const int rBase = m0 + wm*64 + grp * 4;
  const int cBase = n0 + wn*64 + l15;
  #pragma unroll
  for (int fm = 0; fm < 4; ++fm) {
    #pragma unroll
    for (int fn = 0; fn < 4; ++fn) {
      #pragma unroll
      for (int j = 0; j < 4; ++j) {
        int m = rBase + fm*16 + j;
        int n = cBase + fn*16;
        if constexpr (OUTMODE == 0) {
          int b = m >> 11, t = m & 2047, h = n >> 6, d = n & 63;
          size_t idx = vtrans ? (((size_t)(b*H_ + h) * D_ + d) * T_ + t)
                              : (((size_t)(b*H_ + h) * T_ + t) * D_ + d);
          ((bf16*)Ov)[idx] = (bf16)(acc[fm][fn][j] * oscale);
        } else {
          ((float*)Ov)[(size_t)m * C_ + n] = acc[fm][fn][j];
        }
      }
    }
  }
}

// ---------------------------------------------------------------------------
// Flash attention, causal (round-11 structure + setprio around MFMA clusters).
// ---------------------------------------------------------------------------
#define LKV 72

__global__ __launch_bounds__(256)
void attn_fwd(const bf16* __restrict__ Q, const bf16* __restrict__ Km,
              const bf16* __restrict__ Vt, bf16* __restrict__ Oa) {
  __shared__ __align__(16) bf16 Ks [64*LKV];
  __shared__ __align__(16) bf16 Vts[64*LKV];
  __shared__ __align__(16) bf16 Ps [64*LKV];

  const int id = blockIdx.x;
  const int qt = 31 - (id >> 5);
  const int bh = id & 31;
  const int q0 = qt * 64;
  const int tid = threadIdx.x, wid = tid >> 6, lane = tid & 63;
  const int l15 = lane & 15;
  const int grp = lane >> 4;
  const int myrow4 = grp * 4;

  const bf16* Qb = Q  + (size_t)bh * T_ * D_;
  const bf16* Kb = Km + (size_t)bh * T_ * D_;
  const bf16* Vb = Vt + (size_t)bh * D_ * T_;

  const int ksr = tid >> 3, kskc = tid & 7;
  const int kSlot = grp * 8;
  const int b = bh >> 4, h = bh & 15;

  const int qrow = q0 + wid*16 + l15;
  bf16x8 aq0 = *(const bf16x8*)(Qb + (size_t)qrow*64 +      grp*8);
  bf16x8 aq1 = *(const bf16x8*)(Qb + (size_t)qrow*64 + 32 + grp*8);

  f32x4 oacc[4] = {};
  float m_s = NEG_, l_s = 0.f;

  bf16x8 kv_a = *(const bf16x8*)(Kb + (size_t)(ksr)*64      + kskc*8);
  bf16x8 kv_b = *(const bf16x8*)(Kb + (size_t)(ksr + 32)*64 + kskc*8);
  bf16x8 vt_a = *(const bf16x8*)(Vb + (size_t)(ksr     )*T_ + kskc*8);
  bf16x8 vt_b = *(const bf16x8*)(Vb + (size_t)(ksr + 32)*T_ + kskc*8);

  for (int kt = 0; kt <= qt; ++kt) {
    const int kv0 = kt * 64;

    __syncthreads();
    *(bf16x8*)(Ks  + ksr*LKV      + kskc*8) = kv_a;
    *(bf16x8*)(Ks  + (ksr+32)*LKV + kskc*8) = kv_b;
    *(bf16x8*)(Vts + ksr*LKV      + kskc*8) = vt_a;
    *(bf16x8*)(Vts + (ksr+32)*LKV + kskc*8) = vt_b;
    __syncthreads();

    {
      const int kn = (kt < qt) ? kv0 + 64 : kv0;
      kv_a = *(const bf16x8*)(Kb + (size_t)(kn + ksr)*64      + kskc*8);
      kv_b = *(const bf16x8*)(Kb + (size_t)(kn + ksr + 32)*64 + kskc*8);
      vt_a = *(const bf16x8*)(Vb + (size_t)(ksr     )*T_ + kn + kskc*8);
      vt_b = *(const bf16x8*)(Vb + (size_t)(ksr + 32)*T_ + kn + kskc*8);
    }

    f32x4 s[4];
    __builtin_amdgcn_s_setprio(1);
    #pragma unroll
    for (int n = 0; n < 4; ++n) {
      int row = n*16 + l15;
      bf16x8 bk0 = *(const bf16x8*)(Ks + row*LKV      + kSlot);
      bf16x8 bk1 = *(const bf16x8*)(Ks + row*LKV + 32 + kSlot);
      f32x4 a = {};
      a = __builtin_amdgcn_mfma_f32_16x16x32_bf16(bk0, aq0, a, 0, 0, 0);
      a = __builtin_amdgcn_mfma_f32_16x16x32_bf16(bk1, aq1, a, 0, 0, 0);
      s[n] = a;
    }
    __builtin_amdgcn_s_setprio(0);

    float pmax = NEG_;
    if (kt == qt) {
      #pragma unroll
      for (int n = 0; n < 4; ++n)
        #pragma unroll
        for (int j = 0; j < 4; ++j) {
          int kvg = kv0 + n*16 + myrow4 + j;
          float sv = (kvg <= qrow) ? s[n][j] : NEG_;
          s[n][j] = sv;
          pmax = fmaxf(pmax, sv);
        }
    } else {
      #pragma unroll
      for (int n = 0; n < 4; ++n)
        #pragma unroll
        for (int j = 0; j < 4; ++j) pmax = fmaxf(pmax, s[n][j]);
    }
    pmax = fmaxf(pmax, __shfl_xor(pmax, 16));
    pmax = fmaxf(pmax, __shfl_xor(pmax, 32));

    if (__any(pmax > m_s + THR_)) {
      float mnew = fmaxf(m_s, pmax);
      float scold = __builtin_amdgcn_exp2f(m_s - mnew);
      m_s = mnew;
      l_s *= scold;
      #pragma unroll
      for (int j = 0; j < 4; ++j) {
        float scj = __shfl(scold, myrow4 + j);
        #pragma unroll
        for (int n = 0; n < 4; ++n) oacc[n][j] *= scj;
      }
    }

    float ps = 0.f;
    #pragma unroll
    for (int n = 0; n < 4; ++n) {
      bf16x4 pw;
      #pragma unroll
      for (int j = 0; j < 4; ++j) {
        float p = __builtin_amdgcn_exp2f(s[n][j] - m_s);
        ps += p;
        pw[j] = (bf16)p;
      }
      *(bf16x4*)(Ps + (size_t)(wid*16 + l15)*LKV + n*16 + myrow4) = pw;
    }
    ps += __shfl_xor(ps, 16);
    ps += __shfl_xor(ps, 32);
    l_s += ps;

    asm volatile("s_waitcnt lgkmcnt(0)" ::: "memory");
    __builtin_amdgcn_sched_barrier(0);

    int parow = wid*16 + l15;
    bf16x8 pa0 = *(const bf16x8*)(Ps + parow*LKV      + kSlot);
    bf16x8 pa1 = *(const bf16x8*)(Ps + parow*LKV + 32 + kSlot);
    __builtin_amdgcn_s_setprio(1);
    #pragma unroll
    for (int n = 0; n < 4; ++n) {
      int vrow = n*16 + l15;
      bf16x8 bv0 = *(const bf16x8*)(Vts + vrow*LKV      + kSlot);
      bf16x8 bv1 = *(const bf16x8*)(Vts + vrow*LKV + 32 + kSlot);
      oacc[n] = __builtin_amdgcn_mfma_f32_16x16x32_bf16(pa0, bv0, oacc[n], 0, 0, 0);
      oacc[n] = __builtin_amdgcn_mfma_f32_16x16x32_bf16(pa1, bv1, oacc[n], 0, 0, 0);
    }
    __builtin_amdgcn_s_setprio(0);
  }

  const int tg = q0 + wid*16 + myrow4;
  #pragma unroll
  for (int j = 0; j < 4; ++j) {
    float lj = __shfl(l_s, myrow4 + j);
    float inv = 1.f / lj;
    int trow = tg + j;
    #pragma unroll
    for (int n = 0; n < 4; ++n) {
      int ch = h*64 + n*16 + l15;
      Oa[((size_t)(b*T_ + trow)) * C_ + ch] = (bf16)(oacc[n][j] * inv);
    }
  }
}

// ---------------------------------------------------------------------------
extern "C" void kernel_launch(void* const* d_in, const int* in_sizes, int n_in,
                              void* d_out, int out_size, void* d_ws, size_t ws_size,
                              hipStream_t stream) {
  const float* x  = (const float*)d_in[0];
  const float* wq = (const float*)d_in[1];
  const float* wk = (const float*)d_in[2];
  const float* wv = (const float*)d_in[3];
  const float* wo = (const float*)d_in[4];

  bf16* q  = (bf16*)d_ws;                    // [B,H,T,D] bf16 (Q pre-scaled)
  bf16* k  = q  + XB_ELEMS;
  bf16* v  = k  + XB_ELEMS;                  // [B,H,D,T] bf16 (transposed)

  bf16* cvtbuf = (bf16*)d_out;               // bf16 staging inside d_out
  bf16* xb  = cvtbuf;                        // [M,K] bf16
  bf16* wqb = cvtbuf + XB_ELEMS;
  bf16* wkb = wqb + W_ELEMS;
  bf16* wvb = wkb + W_ELEMS;
  bf16* wob = wvb + W_ELEMS;                 // exactly fills d_out

  dim3 blk(256);
  // 0) convert all f32 inputs to bf16 (into d_out)
  cvt5<<<dim3(4096), blk, 0, stream>>>(x, wq, wk, wv, wo, cvtbuf);
  // 1) QKV projections (bf16, glds16, counted-vmcnt pipeline): xb @ W^T -> q,k,v
  gemm_nt<0><<<dim3(768), blk, 0, stream>>>(xb, wqb, wkb, wvb, q, k, v, C_);
  // 2) causal flash attention -> ao bf16 [B,T,C] into xb slot (x dead)
  attn_fwd<<<dim3(1024), blk, 0, stream>>>(q, k, v, xb);
  // 3) relocate ao and wo_bf16 into ws (q,k slots dead after attention)
  hipMemcpyAsync(q, xb,  XB_ELEMS * sizeof(bf16), hipMemcpyDeviceToDevice, stream);
  hipMemcpyAsync(k, wob, W_ELEMS  * sizeof(bf16), hipMemcpyDeviceToDevice, stream);
  // 4) output projection: ao @ wo^T -> f32 d_out
  gemm_nt<1><<<dim3(256), blk, 0, stream>>>(q, k, nullptr, nullptr,
                                            d_out, nullptr, nullptr, C_);
}